// Round 2
// baseline (7872.446 us; speedup 1.0000x reference)
//
#include <hip/hip_runtime.h>
#include <math.h>

typedef __bf16 bf16_t;
typedef __bf16 bf16x4 __attribute__((ext_vector_type(4)));
typedef __bf16 bf16x8 __attribute__((ext_vector_type(8)));
typedef float f32x4 __attribute__((ext_vector_type(4)));
typedef unsigned long long u64;

#define MFMA_16x16x32(A, B, C) __builtin_amdgcn_mfma_f32_16x16x32_bf16((A), (B), (C), 0, 0, 0)

static constexpr int Bn = 64;    // batch
static constexpr int Tn = 512;   // time
static constexpr int Dn = 1024;  // input dim
static constexpr int Hn = 2048;  // hidden
static constexpr int Cn = 5;     // classes
static constexpr int NB = 128;   // scan grid (blocks); 16 cols each

// LDS swizzle for the xw GEMM tiles (32 bf16 = 64B rows)
#define SWZ64(row, kb)  ((((row) * 64) + (kb)) ^ (((row) & 3) << 4))

// ---------------- conversion kernels ----------------
__global__ __launch_bounds__(256) void cvt_bf16_k(const float* __restrict__ in,
                                                  bf16_t* __restrict__ out, int n4) {
  int i = blockIdx.x * 256 + threadIdx.x;
  if (i >= n4) return;
  float4 v = reinterpret_cast<const float4*>(in)[i];
  bf16x4 o;
  o[0] = (bf16_t)v.x; o[1] = (bf16_t)v.y; o[2] = (bf16_t)v.z; o[3] = (bf16_t)v.w;
  reinterpret_cast<bf16x4*>(out)[i] = o;
}

__global__ __launch_bounds__(256) void cvt_hilo_k(const float* __restrict__ in,
                                                  bf16_t* __restrict__ hi,
                                                  bf16_t* __restrict__ lo, int n4) {
  int i = blockIdx.x * 256 + threadIdx.x;
  if (i >= n4) return;
  float4 v = reinterpret_cast<const float4*>(in)[i];
  float f[4] = {v.x, v.y, v.z, v.w};
  bf16x4 h, l;
#pragma unroll
  for (int j = 0; j < 4; ++j) {
    bf16_t hb = (bf16_t)f[j];
    h[j] = hb;
    l[j] = (bf16_t)(f[j] - (float)hb);
  }
  reinterpret_cast<bf16x4*>(hi)[i] = h;
  reinterpret_cast<bf16x4*>(lo)[i] = l;
}

// ---------------- xw projection GEMM ----------------
__global__ __launch_bounds__(256) void gemm_xw_k(const float* __restrict__ A,
                                                 const bf16_t* __restrict__ Bw,
                                                 const float* __restrict__ bias,
                                                 bf16_t* __restrict__ C) {
  constexpr int K = Dn;
  constexpr int N = Hn;
  constexpr int NT = K / 32;
  __shared__ char As[2][128 * 64];
  __shared__ char Bs[2][128 * 64];

  const int tid = threadIdx.x;
  const int lane = tid & 63;
  const int wv = tid >> 6;
  const int wm = (wv >> 1) * 64;
  const int wn = (wv & 1) * 64;
  const int cl = lane & 15;
  const int kh = lane >> 4;
  const long m0 = (long)blockIdx.y * 128;
  const long n0 = (long)blockIdx.x * 128;

  const int srow = tid >> 1;
  const int scolb = (tid & 1) * 32;

  f32x4 acc[4][4] = {};
  float4 pa[4];
  uint4 pb[2];

  auto issue = [&](int kt) {
    const float* ap = A + (m0 + srow) * K + kt * 32 + (tid & 1) * 16;
#pragma unroll
    for (int i = 0; i < 4; ++i) pa[i] = reinterpret_cast<const float4*>(ap)[i];
    const bf16_t* bp = Bw + (n0 + srow) * K + kt * 32 + (tid & 1) * 16;
    pb[0] = reinterpret_cast<const uint4*>(bp)[0];
    pb[1] = reinterpret_cast<const uint4*>(bp)[1];
  };
  auto commit = [&](int buf) {
    bf16x8 a0, a1;
    a0[0] = (bf16_t)pa[0].x; a0[1] = (bf16_t)pa[0].y; a0[2] = (bf16_t)pa[0].z; a0[3] = (bf16_t)pa[0].w;
    a0[4] = (bf16_t)pa[1].x; a0[5] = (bf16_t)pa[1].y; a0[6] = (bf16_t)pa[1].z; a0[7] = (bf16_t)pa[1].w;
    a1[0] = (bf16_t)pa[2].x; a1[1] = (bf16_t)pa[2].y; a1[2] = (bf16_t)pa[2].z; a1[3] = (bf16_t)pa[2].w;
    a1[4] = (bf16_t)pa[3].x; a1[5] = (bf16_t)pa[3].y; a1[6] = (bf16_t)pa[3].z; a1[7] = (bf16_t)pa[3].w;
    *reinterpret_cast<bf16x8*>(&As[buf][SWZ64(srow, scolb)]) = a0;
    *reinterpret_cast<bf16x8*>(&As[buf][SWZ64(srow, scolb + 16)]) = a1;
    *reinterpret_cast<uint4*>(&Bs[buf][SWZ64(srow, scolb)]) = pb[0];
    *reinterpret_cast<uint4*>(&Bs[buf][SWZ64(srow, scolb + 16)]) = pb[1];
  };

  issue(0);
  commit(0);
  for (int kt = 0; kt < NT; ++kt) {
    const int buf = kt & 1;
    __syncthreads();
    if (kt + 1 < NT) issue(kt + 1);
    bf16x8 af[4], bfr[4];
#pragma unroll
    for (int i = 0; i < 4; ++i)
      af[i] = *reinterpret_cast<const bf16x8*>(&As[buf][SWZ64(wm + i * 16 + cl, kh * 16)]);
#pragma unroll
    for (int j = 0; j < 4; ++j)
      bfr[j] = *reinterpret_cast<const bf16x8*>(&Bs[buf][SWZ64(wn + j * 16 + cl, kh * 16)]);
#pragma unroll
    for (int i = 0; i < 4; ++i)
#pragma unroll
      for (int j = 0; j < 4; ++j)
        acc[i][j] = MFMA_16x16x32(af[i], bfr[j], acc[i][j]);
    if (kt + 1 < NT) commit((kt + 1) & 1);
  }

  const int rl4 = kh * 4;
#pragma unroll
  for (int j = 0; j < 4; ++j) {
    const long gcol = n0 + wn + j * 16 + cl;
    const float bv = bias[gcol];
#pragma unroll
    for (int i = 0; i < 4; ++i) {
      const long grow = m0 + wm + i * 16 + rl4;
#pragma unroll
      for (int q = 0; q < 4; ++q)
        C[(grow + q) * N + gcol] = (bf16_t)(acc[i][j][q] + bv);
    }
  }
}

// ---------------- persistent scan kernel ----------------
// 128 blocks x 256 threads, 1 block/CU. Block owns 16 output columns; U hi+lo
// slice lives in 128KB dynamic LDS for all 512 steps.
//
// Coherence scheme (round 1, kept):
//   h STORES : sc0 sc1 write-through relaxed agent atomics -> land at MALL.
//   h LOADS  : plain cached 16-B loads, made coherent by a per-step
//              post-poll agent ACQUIRE fence (buffer_inv only; nothing dirty).
//
// Round-2 changes:
//   1. DENSE FLAGS + WIDE POLL + THROTTLE. Flags are unsigned[128] packed in
//      8 cache lines. Wave 0 polls ALL 128 flags with a single u64 load per
//      lane (8 coalesced line requests/iter vs 128 scattered before), with
//      s_sleep between failed polls. Theory: the old scattered poll flood
//      (~16K MALL reqs per ~600cy grid-wide) was inflating the latency of
//      every serial-chain MALL access (h store ack, flag, cold h loads).
//   2. PERSISTENT U FRAGMENTS. U is constant across all 512 steps; the first
//      16 k-pair iterations' B-fragments (256 VGPRs) are read from LDS once
//      and held in registers forever. Halves per-step LDS traffic and feeds
//      MFMAs immediately while cold h loads are in flight. 1 block/CU ->
//      1 wave/SIMD -> ~450 VGPRs safe.
__global__ __launch_bounds__(256, 1) void scan_k(
    const bf16_t* __restrict__ Uhi, const bf16_t* __restrict__ Ulo,
    const float* __restrict__ Ub, const bf16_t* __restrict__ XW,
    bf16_t* __restrict__ H0, bf16_t* __restrict__ H1,
    const bf16_t* __restrict__ V1w, const float* __restrict__ V1b,
    float* __restrict__ Z1,
    const float* __restrict__ V2w, const float* __restrict__ V2b,
    float* __restrict__ out, unsigned* __restrict__ slots) {
  extern __shared__ char smem[];
  char* Uh_s = smem;                          // 64 KB
  char* Ul_s = smem + 65536;                  // 64 KB
  bf16_t* hscr = (bf16_t*)(smem + 131072);    // 2 KB store-transpose scratch

  const int tid = threadIdx.x;
  const int lane = tid & 63;
  const int wv = tid >> 6;
  const int cl = lane & 15;
  const int kh = lane >> 4;
  const int n0 = blockIdx.x * 16;

  // ---- stage U slice into LDS (once) ----
  {
    const int col = tid >> 4;
    const int seg = tid & 15;
    const char* srch = reinterpret_cast<const char*>(Uhi + (long)(n0 + col) * Hn);
    const char* srcl = reinterpret_cast<const char*>(Ulo + (long)(n0 + col) * Hn);
#pragma unroll
    for (int c = 0; c < 16; ++c) {
      const int byteoff = seg * 16 + c * 256;
      uint4 vh = *reinterpret_cast<const uint4*>(srch + byteoff);
      uint4 vl = *reinterpret_cast<const uint4*>(srcl + byteoff);
      const int sw = col * 4096 + (byteoff ^ ((col & 7) << 4));
      *reinterpret_cast<uint4*>(Uh_s + sw) = vh;
      *reinterpret_cast<uint4*>(Ul_s + sw) = vl;
    }
  }
  __syncthreads();

  const float bv = Ub[n0 + cl];
  const int mrow = 16 * wv + kh * 4;  // lane's 4 output rows
  const int lds_base = cl * 4096;
  const int lds_x = (cl & 7) << 4;
  // store-side mapping: one coalesced u64 (4 bf16 cols) per lane
  const int st_row = lane >> 2;       // 0..15
  const int st_cg = lane & 3;         // col group *4

  // ---- persistent U fragments for kf = 0..31 (first 16 pair-iters) ----
  // Read from LDS exactly once; live in VGPRs for all 512 steps.
  bf16x8 Ur0[16], Ur1[16], Ur2[16], Ur3[16];
#pragma unroll
  for (int p = 0; p < 16; ++p) {
    const int kb0 = (2 * p) * 64 + kh * 16;
    const int kb1 = kb0 + 64;
    Ur0[p] = *reinterpret_cast<const bf16x8*>(Uh_s + lds_base + (kb0 ^ lds_x));
    Ur1[p] = *reinterpret_cast<const bf16x8*>(Ul_s + lds_base + (kb0 ^ lds_x));
    Ur2[p] = *reinterpret_cast<const bf16x8*>(Uh_s + lds_base + (kb1 ^ lds_x));
    Ur3[p] = *reinterpret_cast<const bf16x8*>(Ul_s + lds_base + (kb1 ^ lds_x));
  }

  // prefetch xw add-path for t=0
  bf16_t ad[4];
#pragma unroll
  for (int q = 0; q < 4; ++q)
    ad[q] = XW[(long)(mrow + q) * (Tn * Hn) + n0 + cl];

  for (int t = 0; t < Tn; ++t) {
    const bf16_t* hin = (t & 1) ? H1 : H0;
    bf16_t* hout = (t & 1) ? H0 : H1;

    const bf16_t* arow = hin + (16 * wv + cl) * Hn + kh * 8;

    f32x4 ah0 = {}, ah1 = {}, al0 = {}, al1 = {};
    // first half of k: U operands already in registers (no LDS reads)
#pragma unroll
    for (int p = 0; p < 16; ++p) {
      bf16x8 a0 = *reinterpret_cast<const bf16x8*>(arow + (2 * p) * 32);
      bf16x8 a1 = *reinterpret_cast<const bf16x8*>(arow + (2 * p) * 32 + 32);
      ah0 = MFMA_16x16x32(a0, Ur0[p], ah0);
      al0 = MFMA_16x16x32(a0, Ur1[p], al0);
      ah1 = MFMA_16x16x32(a1, Ur2[p], ah1);
      al1 = MFMA_16x16x32(a1, Ur3[p], al1);
    }
    // second half of k: U operands from LDS
#pragma unroll 8
    for (int kf = 32; kf < 64; kf += 2) {
      bf16x8 a0 = *reinterpret_cast<const bf16x8*>(arow + kf * 32);
      bf16x8 a1 = *reinterpret_cast<const bf16x8*>(arow + kf * 32 + 32);
      const int kb0 = kf * 64 + kh * 16;
      const int kb1 = kb0 + 64;
      bf16x8 bh0 = *reinterpret_cast<const bf16x8*>(Uh_s + lds_base + (kb0 ^ lds_x));
      bf16x8 bl0 = *reinterpret_cast<const bf16x8*>(Ul_s + lds_base + (kb0 ^ lds_x));
      bf16x8 bh1 = *reinterpret_cast<const bf16x8*>(Uh_s + lds_base + (kb1 ^ lds_x));
      bf16x8 bl1 = *reinterpret_cast<const bf16x8*>(Ul_s + lds_base + (kb1 ^ lds_x));
      ah0 = MFMA_16x16x32(a0, bh0, ah0);
      al0 = MFMA_16x16x32(a0, bl0, al0);
      ah1 = MFMA_16x16x32(a1, bh1, ah1);
      al1 = MFMA_16x16x32(a1, bl1, al1);
    }

    // epilogue -> LDS transpose -> one coalesced u64 agent-scope store per lane
#pragma unroll
    for (int q = 0; q < 4; ++q) {
      float v = ah0[q] + ah1[q] + al0[q] + al1[q] + bv + (float)ad[q];
      hscr[wv * 256 + (kh * 4 + q) * 16 + cl] = (bf16_t)fmaxf(v, 0.f);
    }
    asm volatile("s_waitcnt lgkmcnt(0)" ::: "memory");
    {
      u64 val = *reinterpret_cast<const u64*>(&hscr[wv * 256 + st_row * 16 + st_cg * 4]);
      __hip_atomic_store(
          reinterpret_cast<u64*>(hout + (long)(16 * wv + st_row) * Hn + n0 + st_cg * 4),
          val, __ATOMIC_RELAXED, __HIP_MEMORY_SCOPE_AGENT);
    }

    // ---- broadcast grid barrier (dense flags, wide poll, throttled) ----
    const unsigned tgt = (unsigned)(t + 1);
    __syncthreads();  // drains vmcnt(0): all sc1 h-stores acked at coherence point
    asm volatile("" ::: "memory");
    if (tid == 0)
      __hip_atomic_store(slots + blockIdx.x, tgt,
                         __ATOMIC_RELAXED, __HIP_MEMORY_SCOPE_AGENT);

    // prefetch XW for t+1 — hides under the poll
    bf16_t adn[4];
    if (t + 1 < Tn) {
#pragma unroll
      for (int q = 0; q < 4; ++q)
        adn[q] = XW[(long)(mrow + q) * (Tn * Hn) + (long)(t + 1) * Hn + n0 + cl];
    }

    if (tid < 64) {  // wave 0: each lane reads 2 packed flags in ONE u64 load
      const u64* fl = reinterpret_cast<const u64*>(slots);
      for (;;) {
        u64 v = __hip_atomic_load(fl + tid, __ATOMIC_RELAXED,
                                  __HIP_MEMORY_SCOPE_AGENT);
        if (__all(((unsigned)v >= tgt) && ((unsigned)(v >> 32) >= tgt))) break;
        __builtin_amdgcn_s_sleep(2);  // throttle MALL pressure while waiting
      }
      // acquire: buffer_inv (no dirty lines -> no wbl2). Makes the next
      // step's plain cached h loads coherent for the whole CU/XCD.
      __builtin_amdgcn_fence(__ATOMIC_ACQUIRE, "agent");
    }
    asm volatile("" ::: "memory");
    __syncthreads();  // orders waves 1..3's loads after wave 0's inv

#pragma unroll
    for (int q = 0; q < 4; ++q) ad[q] = adn[q];
  }

  // ---- V1 layer: z1 = relu(h_last @ V1^T + b1), f32 out (h_last = H0) ----
  {
    const bf16_t* arow = H0 + (16 * wv + cl) * Hn + kh * 8;
    const bf16_t* vrow = V1w + (long)(n0 + cl) * Hn + kh * 8;
    f32x4 z0 = {}, z1a = {};
#pragma unroll 4
    for (int kf = 0; kf < 64; kf += 2) {
      bf16x8 a0 = *reinterpret_cast<const bf16x8*>(arow + kf * 32);
      bf16x8 a1 = *reinterpret_cast<const bf16x8*>(arow + kf * 32 + 32);
      bf16x8 b0 = *reinterpret_cast<const bf16x8*>(vrow + kf * 32);
      bf16x8 b1 = *reinterpret_cast<const bf16x8*>(vrow + kf * 32 + 32);
      z0 = MFMA_16x16x32(a0, b0, z0);
      z1a = MFMA_16x16x32(a1, b1, z1a);
    }
    const float v1bv = V1b[n0 + cl];
#pragma unroll
    for (int q = 0; q < 4; ++q)
      Z1[(long)(mrow + q) * Hn + n0 + cl] = fmaxf(z0[q] + z1a[q] + v1bv, 0.f);
  }

  // barrier before head reads Z1 — FULL fences here (once): Z1 was written with
  // plain cached stores, so release (wbl2) + acquire (inv) are required.
  {
    const unsigned tgt = (unsigned)(Tn + 1);
    __syncthreads();
    if (tid == 0)
      __hip_atomic_store(slots + blockIdx.x, tgt,
                         __ATOMIC_RELEASE, __HIP_MEMORY_SCOPE_AGENT);
    if (tid < 64) {
      const u64* fl = reinterpret_cast<const u64*>(slots);
      for (;;) {
        u64 v = __hip_atomic_load(fl + tid, __ATOMIC_RELAXED,
                                  __HIP_MEMORY_SCOPE_AGENT);
        if (__all(((unsigned)v >= tgt) && ((unsigned)(v >> 32) >= tgt))) break;
        __builtin_amdgcn_s_sleep(2);
      }
      __builtin_amdgcn_fence(__ATOMIC_ACQUIRE, "agent");
    }
    __syncthreads();
  }

  // ---- head: z2 = relu(z1 @ V2^T + b2); out = log_softmax ----
  if (blockIdx.x < Bn) {
    const int b = blockIdx.x;
    float p[Cn] = {0.f, 0.f, 0.f, 0.f, 0.f};
    for (int j = tid; j < Hn; j += 256) {
      const float x = Z1[(long)b * Hn + j];
#pragma unroll
      for (int c = 0; c < Cn; ++c) p[c] += x * V2w[(long)c * Hn + j];
    }
#pragma unroll
    for (int c = 0; c < Cn; ++c)
      for (int off = 32; off; off >>= 1) p[c] += __shfl_down(p[c], off, 64);

    float* red = reinterpret_cast<float*>(smem);
    if (lane == 0) {
#pragma unroll
      for (int c = 0; c < Cn; ++c) red[c * 4 + wv] = p[c];
    }
    __syncthreads();
    if (tid == 0) {
      float z[Cn];
      float mx = 0.f;
#pragma unroll
      for (int c = 0; c < Cn; ++c) {
        z[c] = red[c * 4 + 0] + red[c * 4 + 1] + red[c * 4 + 2] + red[c * 4 + 3] + V2b[c];
        z[c] = fmaxf(z[c], 0.f);
        mx = fmaxf(mx, z[c]);
      }
      float s = 0.f;
#pragma unroll
      for (int c = 0; c < Cn; ++c) s += expf(z[c] - mx);
      const float ls = logf(s);
#pragma unroll
      for (int c = 0; c < Cn; ++c) out[b * Cn + c] = z[c] - mx - ls;
    }
  }
}

// ---------------- host ----------------
extern "C" void kernel_launch(void* const* d_in, const int* in_sizes, int n_in,
                              void* d_out, int out_size, void* d_ws, size_t ws_size,
                              hipStream_t stream) {
  const float* inputs = (const float*)d_in[0];
  const float* W_w = (const float*)d_in[1];
  const float* W_b = (const float*)d_in[2];
  const float* U_w = (const float*)d_in[3];
  const float* U_b = (const float*)d_in[4];
  const float* V1_w = (const float*)d_in[5];
  const float* V1_b = (const float*)d_in[6];
  const float* V2_w = (const float*)d_in[7];
  const float* V2_b = (const float*)d_in[8];
  float* out = (float*)d_out;

  size_t off = 0;
  auto alloc = [&](size_t bytes) {
    void* p = (char*)d_ws + off;
    off += (bytes + 255) & ~(size_t)255;
    return p;
  };
  bf16_t* Wbf = (bf16_t*)alloc((size_t)Hn * Dn * 2);
  bf16_t* Uhi = (bf16_t*)alloc((size_t)Hn * Hn * 2);
  bf16_t* Ulo = (bf16_t*)alloc((size_t)Hn * Hn * 2);
  bf16_t* V1bf = (bf16_t*)alloc((size_t)Hn * Hn * 2);
  bf16_t* XW = (bf16_t*)alloc((size_t)Bn * Tn * Hn * 2);
  bf16_t* Ha = (bf16_t*)alloc((size_t)Bn * Hn * 2);
  bf16_t* Hb = (bf16_t*)alloc((size_t)Bn * Hn * 2);
  float* Z1 = (float*)alloc((size_t)Bn * Hn * 4);
  unsigned* slots = (unsigned*)alloc((size_t)4096);  // dense flags: NB*4 = 512 B used
  (void)ws_size;

  (void)hipFuncSetAttribute((const void*)scan_k,
                            hipFuncAttributeMaxDynamicSharedMemorySize, 133120);

  cvt_bf16_k<<<(Hn * Dn / 4 + 255) / 256, 256, 0, stream>>>(W_w, Wbf, Hn * Dn / 4);
  cvt_hilo_k<<<(Hn * Hn / 4 + 255) / 256, 256, 0, stream>>>(U_w, Uhi, Ulo, Hn * Hn / 4);
  cvt_bf16_k<<<(Hn * Hn / 4 + 255) / 256, 256, 0, stream>>>(V1_w, V1bf, Hn * Hn / 4);

  gemm_xw_k<<<dim3(Hn / 128, (Bn * Tn) / 128), 256, 0, stream>>>(inputs, Wbf, W_b, XW);

  (void)hipMemsetAsync(Ha, 0, (size_t)Bn * Hn * 2, stream);
  (void)hipMemsetAsync(slots, 0, (size_t)4096, stream);

  scan_k<<<NB, 256, 133120, stream>>>(Uhi, Ulo, U_b, XW, Ha, Hb, V1bf, V1_b, Z1,
                                      V2_w, V2_b, out, slots);
}

// Round 3
// 6799.406 us; speedup vs baseline: 1.1578x; 1.1578x over previous
//
#include <hip/hip_runtime.h>
#include <math.h>

typedef __bf16 bf16_t;
typedef __bf16 bf16x4 __attribute__((ext_vector_type(4)));
typedef __bf16 bf16x8 __attribute__((ext_vector_type(8)));
typedef float f32x4 __attribute__((ext_vector_type(4)));
typedef unsigned long long u64;

#define MFMA_16x16x32(A, B, C) __builtin_amdgcn_mfma_f32_16x16x32_bf16((A), (B), (C), 0, 0, 0)

static constexpr int Bn = 64;    // batch
static constexpr int Tn = 512;   // time
static constexpr int Dn = 1024;  // input dim
static constexpr int Hn = 2048;  // hidden
static constexpr int Cn = 5;     // classes
static constexpr int NB = 128;   // scan grid (blocks); 16 cols each

// LDS swizzle for the xw GEMM tiles (32 bf16 = 64B rows)
#define SWZ64(row, kb)  ((((row) * 64) + (kb)) ^ (((row) & 3) << 4))

// ---------------- conversion kernels ----------------
__global__ __launch_bounds__(256) void cvt_bf16_k(const float* __restrict__ in,
                                                  bf16_t* __restrict__ out, int n4) {
  int i = blockIdx.x * 256 + threadIdx.x;
  if (i >= n4) return;
  float4 v = reinterpret_cast<const float4*>(in)[i];
  bf16x4 o;
  o[0] = (bf16_t)v.x; o[1] = (bf16_t)v.y; o[2] = (bf16_t)v.z; o[3] = (bf16_t)v.w;
  reinterpret_cast<bf16x4*>(out)[i] = o;
}

__global__ __launch_bounds__(256) void cvt_hilo_k(const float* __restrict__ in,
                                                  bf16_t* __restrict__ hi,
                                                  bf16_t* __restrict__ lo, int n4) {
  int i = blockIdx.x * 256 + threadIdx.x;
  if (i >= n4) return;
  float4 v = reinterpret_cast<const float4*>(in)[i];
  float f[4] = {v.x, v.y, v.z, v.w};
  bf16x4 h, l;
#pragma unroll
  for (int j = 0; j < 4; ++j) {
    bf16_t hb = (bf16_t)f[j];
    h[j] = hb;
    l[j] = (bf16_t)(f[j] - (float)hb);
  }
  reinterpret_cast<bf16x4*>(hi)[i] = h;
  reinterpret_cast<bf16x4*>(lo)[i] = l;
}

// ---------------- xw projection GEMM ----------------
__global__ __launch_bounds__(256) void gemm_xw_k(const float* __restrict__ A,
                                                 const bf16_t* __restrict__ Bw,
                                                 const float* __restrict__ bias,
                                                 bf16_t* __restrict__ C) {
  constexpr int K = Dn;
  constexpr int N = Hn;
  constexpr int NT = K / 32;
  __shared__ char As[2][128 * 64];
  __shared__ char Bs[2][128 * 64];

  const int tid = threadIdx.x;
  const int lane = tid & 63;
  const int wv = tid >> 6;
  const int wm = (wv >> 1) * 64;
  const int wn = (wv & 1) * 64;
  const int cl = lane & 15;
  const int kh = lane >> 4;
  const long m0 = (long)blockIdx.y * 128;
  const long n0 = (long)blockIdx.x * 128;

  const int srow = tid >> 1;
  const int scolb = (tid & 1) * 32;

  f32x4 acc[4][4] = {};
  float4 pa[4];
  uint4 pb[2];

  auto issue = [&](int kt) {
    const float* ap = A + (m0 + srow) * K + kt * 32 + (tid & 1) * 16;
#pragma unroll
    for (int i = 0; i < 4; ++i) pa[i] = reinterpret_cast<const float4*>(ap)[i];
    const bf16_t* bp = Bw + (n0 + srow) * K + kt * 32 + (tid & 1) * 16;
    pb[0] = reinterpret_cast<const uint4*>(bp)[0];
    pb[1] = reinterpret_cast<const uint4*>(bp)[1];
  };
  auto commit = [&](int buf) {
    bf16x8 a0, a1;
    a0[0] = (bf16_t)pa[0].x; a0[1] = (bf16_t)pa[0].y; a0[2] = (bf16_t)pa[0].z; a0[3] = (bf16_t)pa[0].w;
    a0[4] = (bf16_t)pa[1].x; a0[5] = (bf16_t)pa[1].y; a0[6] = (bf16_t)pa[1].z; a0[7] = (bf16_t)pa[1].w;
    a1[0] = (bf16_t)pa[2].x; a1[1] = (bf16_t)pa[2].y; a1[2] = (bf16_t)pa[2].z; a1[3] = (bf16_t)pa[2].w;
    a1[4] = (bf16_t)pa[3].x; a1[5] = (bf16_t)pa[3].y; a1[6] = (bf16_t)pa[3].z; a1[7] = (bf16_t)pa[3].w;
    *reinterpret_cast<bf16x8*>(&As[buf][SWZ64(srow, scolb)]) = a0;
    *reinterpret_cast<bf16x8*>(&As[buf][SWZ64(srow, scolb + 16)]) = a1;
    *reinterpret_cast<uint4*>(&Bs[buf][SWZ64(srow, scolb)]) = pb[0];
    *reinterpret_cast<uint4*>(&Bs[buf][SWZ64(srow, scolb + 16)]) = pb[1];
  };

  issue(0);
  commit(0);
  for (int kt = 0; kt < NT; ++kt) {
    const int buf = kt & 1;
    __syncthreads();
    if (kt + 1 < NT) issue(kt + 1);
    bf16x8 af[4], bfr[4];
#pragma unroll
    for (int i = 0; i < 4; ++i)
      af[i] = *reinterpret_cast<const bf16x8*>(&As[buf][SWZ64(wm + i * 16 + cl, kh * 16)]);
#pragma unroll
    for (int j = 0; j < 4; ++j)
      bfr[j] = *reinterpret_cast<const bf16x8*>(&Bs[buf][SWZ64(wn + j * 16 + cl, kh * 16)]);
#pragma unroll
    for (int i = 0; i < 4; ++i)
#pragma unroll
      for (int j = 0; j < 4; ++j)
        acc[i][j] = MFMA_16x16x32(af[i], bfr[j], acc[i][j]);
    if (kt + 1 < NT) commit((kt + 1) & 1);
  }

  const int rl4 = kh * 4;
#pragma unroll
  for (int j = 0; j < 4; ++j) {
    const long gcol = n0 + wn + j * 16 + cl;
    const float bv = bias[gcol];
#pragma unroll
    for (int i = 0; i < 4; ++i) {
      const long grow = m0 + wm + i * 16 + rl4;
#pragma unroll
      for (int q = 0; q < 4; ++q)
        C[(grow + q) * N + gcol] = (bf16_t)(acc[i][j][q] + bv);
    }
  }
}

// ---------------- persistent scan kernel ----------------
// 128 blocks x 256 threads, 1 block/CU. Block owns 16 output columns; U hi+lo
// slice lives in 128KB dynamic LDS for all 512 steps.
//
// Round-3 coherence scheme: ADDRESS ROTATION (rot=1 path).
//   h_t lives at its own virgin slot Hc + t*Hstep (513 slots, ~128MB ws).
//   h STORES : sc0 sc1 write-through relaxed agent atomics -> acked at MALL
//              before the flag (unchanged protocol).
//   h LOADS  : PLAIN CACHED loads with NO per-step fence. Correct because a
//              virgin address can never have a stale L1/L2 copy; first reader
//              per XCD misses to MALL, the other 15 blocks hit L2.
//   This removes the 128 per-step full-L2 buffer_invs of round 1 (the theory
//   for the hidden ~2x latency multiplier) and keeps XW/V1w L2-resident.
// Fallback (rot=0, if ws too small): ping-pong 2 slots + per-step acquire
//   fence = exact round-1 semantics.
__global__ __launch_bounds__(256, 1) void scan_k(
    const bf16_t* __restrict__ Uhi, const bf16_t* __restrict__ Ulo,
    const float* __restrict__ Ub, const bf16_t* __restrict__ XW,
    bf16_t* __restrict__ Hc, long Hstep, int rot,
    const bf16_t* __restrict__ V1w, const float* __restrict__ V1b,
    float* __restrict__ Z1,
    const float* __restrict__ V2w, const float* __restrict__ V2b,
    float* __restrict__ out, unsigned* __restrict__ slots) {
  extern __shared__ char smem[];
  char* Uh_s = smem;                          // 64 KB
  char* Ul_s = smem + 65536;                  // 64 KB
  bf16_t* hscr = (bf16_t*)(smem + 131072);    // 2 KB store-transpose scratch

  const int tid = threadIdx.x;
  const int lane = tid & 63;
  const int wv = tid >> 6;
  const int cl = lane & 15;
  const int kh = lane >> 4;
  const int n0 = blockIdx.x * 16;

  // ---- stage U slice into LDS (once) ----
  {
    const int col = tid >> 4;
    const int seg = tid & 15;
    const char* srch = reinterpret_cast<const char*>(Uhi + (long)(n0 + col) * Hn);
    const char* srcl = reinterpret_cast<const char*>(Ulo + (long)(n0 + col) * Hn);
#pragma unroll
    for (int c = 0; c < 16; ++c) {
      const int byteoff = seg * 16 + c * 256;
      uint4 vh = *reinterpret_cast<const uint4*>(srch + byteoff);
      uint4 vl = *reinterpret_cast<const uint4*>(srcl + byteoff);
      const int sw = col * 4096 + (byteoff ^ ((col & 7) << 4));
      *reinterpret_cast<uint4*>(Uh_s + sw) = vh;
      *reinterpret_cast<uint4*>(Ul_s + sw) = vl;
    }
  }
  __syncthreads();

  const float bv = Ub[n0 + cl];
  const int mrow = 16 * wv + kh * 4;  // lane's 4 output rows
  const int lds_base = cl * 4096;
  const int lds_x = (cl & 7) << 4;
  // store-side mapping: one coalesced u64 (4 bf16 cols) per lane
  const int st_row = lane >> 2;       // 0..15
  const int st_cg = lane & 3;         // col group *4

  // prefetch xw add-path for t=0
  bf16_t ad[4];
#pragma unroll
  for (int q = 0; q < 4; ++q)
    ad[q] = XW[(long)(mrow + q) * (Tn * Hn) + n0 + cl];

  // h slot pointers: t reads hin, writes hout.
  bf16_t* hin = Hc;            // slot 0 = zeros
  bf16_t* hout = Hc + Hstep;   // slot 1

  for (int t = 0; t < Tn; ++t) {
    const bf16_t* arow = hin + (16 * wv + cl) * Hn + kh * 8;

    f32x4 ah0 = {}, ah1 = {}, al0 = {}, al1 = {};
#pragma unroll 8
    for (int kf = 0; kf < 64; kf += 2) {
      // plain cached 16-B loads: fresh by construction (virgin slot address)
      bf16x8 a0 = *reinterpret_cast<const bf16x8*>(arow + kf * 32);
      bf16x8 a1 = *reinterpret_cast<const bf16x8*>(arow + kf * 32 + 32);
      const int kb0 = kf * 64 + kh * 16;
      const int kb1 = kb0 + 64;
      bf16x8 bh0 = *reinterpret_cast<const bf16x8*>(Uh_s + lds_base + (kb0 ^ lds_x));
      bf16x8 bl0 = *reinterpret_cast<const bf16x8*>(Ul_s + lds_base + (kb0 ^ lds_x));
      bf16x8 bh1 = *reinterpret_cast<const bf16x8*>(Uh_s + lds_base + (kb1 ^ lds_x));
      bf16x8 bl1 = *reinterpret_cast<const bf16x8*>(Ul_s + lds_base + (kb1 ^ lds_x));
      ah0 = MFMA_16x16x32(a0, bh0, ah0);
      al0 = MFMA_16x16x32(a0, bl0, al0);
      ah1 = MFMA_16x16x32(a1, bh1, ah1);
      al1 = MFMA_16x16x32(a1, bl1, al1);
    }

    // epilogue -> LDS transpose -> one coalesced u64 agent-scope store per lane
#pragma unroll
    for (int q = 0; q < 4; ++q) {
      float v = ah0[q] + ah1[q] + al0[q] + al1[q] + bv + (float)ad[q];
      hscr[wv * 256 + (kh * 4 + q) * 16 + cl] = (bf16_t)fmaxf(v, 0.f);
    }
    asm volatile("s_waitcnt lgkmcnt(0)" ::: "memory");
    {
      u64 val = *reinterpret_cast<const u64*>(&hscr[wv * 256 + st_row * 16 + st_cg * 4]);
      __hip_atomic_store(
          reinterpret_cast<u64*>(hout + (long)(16 * wv + st_row) * Hn + n0 + st_cg * 4),
          val, __ATOMIC_RELAXED, __HIP_MEMORY_SCOPE_AGENT);
    }

    // ---- fence-free broadcast grid barrier (round-1 protocol, unchanged) ----
    const unsigned tgt = (unsigned)(t + 1);
    __syncthreads();  // drains vmcnt(0): all sc1 h-stores acked at coherence point
    asm volatile("" ::: "memory");
    if (tid == 0)
      __hip_atomic_store(slots + (size_t)blockIdx.x * 32, tgt,
                         __ATOMIC_RELAXED, __HIP_MEMORY_SCOPE_AGENT);

    // prefetch XW for t+1 — hides under the poll
    bf16_t adn[4];
    if (t + 1 < Tn) {
#pragma unroll
      for (int q = 0; q < 4; ++q)
        adn[q] = XW[(long)(mrow + q) * (Tn * Hn) + (long)(t + 1) * Hn + n0 + cl];
    }

    if (tid < 64) {  // wave 0 polls all 128 slots (sc1 loads -> always MALL)
      for (;;) {
        unsigned a = __hip_atomic_load(slots + (size_t)tid * 32,
                                       __ATOMIC_RELAXED, __HIP_MEMORY_SCOPE_AGENT);
        unsigned b = __hip_atomic_load(slots + (size_t)(tid + 64) * 32,
                                       __ATOMIC_RELAXED, __HIP_MEMORY_SCOPE_AGENT);
        if (__all((a >= tgt) && (b >= tgt))) break;
      }
      // rotation: no fence needed (virgin addresses can't be stale).
      // fallback ping-pong: acquire = buffer_inv, round-1 semantics.
      if (!rot) __builtin_amdgcn_fence(__ATOMIC_ACQUIRE, "agent");
    }
    asm volatile("" ::: "memory");
    __syncthreads();

#pragma unroll
    for (int q = 0; q < 4; ++q) ad[q] = adn[q];

    // advance slots
    bf16_t* nn = hout;
    hout = rot ? (hout + Hstep) : hin;
    hin = nn;
  }

  // ---- V1 layer: z1 = relu(h_last @ V1^T + b1), f32 out (h_last = hin) ----
  // Plain loads OK: final slot is virgin (rot) or post-fence (fallback).
  {
    const bf16_t* arow = hin + (16 * wv + cl) * Hn + kh * 8;
    const bf16_t* vrow = V1w + (long)(n0 + cl) * Hn + kh * 8;
    f32x4 z0 = {}, z1a = {};
#pragma unroll 4
    for (int kf = 0; kf < 64; kf += 2) {
      bf16x8 a0 = *reinterpret_cast<const bf16x8*>(arow + kf * 32);
      bf16x8 a1 = *reinterpret_cast<const bf16x8*>(arow + kf * 32 + 32);
      bf16x8 b0 = *reinterpret_cast<const bf16x8*>(vrow + kf * 32);
      bf16x8 b1 = *reinterpret_cast<const bf16x8*>(vrow + kf * 32 + 32);
      z0 = MFMA_16x16x32(a0, b0, z0);
      z1a = MFMA_16x16x32(a1, b1, z1a);
    }
    const float v1bv = V1b[n0 + cl];
#pragma unroll
    for (int q = 0; q < 4; ++q)
      Z1[(long)(mrow + q) * Hn + n0 + cl] = fmaxf(z0[q] + z1a[q] + v1bv, 0.f);
  }

  // barrier before head reads Z1 — FULL fences here (once): Z1 was written with
  // plain cached stores, so release (wbl2) + acquire (inv) are required.
  {
    const unsigned tgt = (unsigned)(Tn + 1);
    __syncthreads();
    if (tid == 0)
      __hip_atomic_store(slots + (size_t)blockIdx.x * 32, tgt,
                         __ATOMIC_RELEASE, __HIP_MEMORY_SCOPE_AGENT);
    if (tid < 64) {
      for (;;) {
        unsigned a = __hip_atomic_load(slots + (size_t)tid * 32,
                                       __ATOMIC_RELAXED, __HIP_MEMORY_SCOPE_AGENT);
        unsigned b = __hip_atomic_load(slots + (size_t)(tid + 64) * 32,
                                       __ATOMIC_RELAXED, __HIP_MEMORY_SCOPE_AGENT);
        if (__all((a >= tgt) && (b >= tgt))) break;
      }
      __builtin_amdgcn_fence(__ATOMIC_ACQUIRE, "agent");
    }
    __syncthreads();
  }

  // ---- head: z2 = relu(z1 @ V2^T + b2); out = log_softmax ----
  if (blockIdx.x < Bn) {
    const int b = blockIdx.x;
    float p[Cn] = {0.f, 0.f, 0.f, 0.f, 0.f};
    for (int j = tid; j < Hn; j += 256) {
      const float x = Z1[(long)b * Hn + j];
#pragma unroll
      for (int c = 0; c < Cn; ++c) p[c] += x * V2w[(long)c * Hn + j];
    }
#pragma unroll
    for (int c = 0; c < Cn; ++c)
      for (int off = 32; off; off >>= 1) p[c] += __shfl_down(p[c], off, 64);

    float* red = reinterpret_cast<float*>(smem);
    if (lane == 0) {
#pragma unroll
      for (int c = 0; c < Cn; ++c) red[c * 4 + wv] = p[c];
    }
    __syncthreads();
    if (tid == 0) {
      float z[Cn];
      float mx = 0.f;
#pragma unroll
      for (int c = 0; c < Cn; ++c) {
        z[c] = red[c * 4 + 0] + red[c * 4 + 1] + red[c * 4 + 2] + red[c * 4 + 3] + V2b[c];
        z[c] = fmaxf(z[c], 0.f);
        mx = fmaxf(mx, z[c]);
      }
      float s = 0.f;
#pragma unroll
      for (int c = 0; c < Cn; ++c) s += expf(z[c] - mx);
      const float ls = logf(s);
#pragma unroll
      for (int c = 0; c < Cn; ++c) out[b * Cn + c] = z[c] - mx - ls;
    }
  }
}

// ---------------- host ----------------
extern "C" void kernel_launch(void* const* d_in, const int* in_sizes, int n_in,
                              void* d_out, int out_size, void* d_ws, size_t ws_size,
                              hipStream_t stream) {
  const float* inputs = (const float*)d_in[0];
  const float* W_w = (const float*)d_in[1];
  const float* W_b = (const float*)d_in[2];
  const float* U_w = (const float*)d_in[3];
  const float* U_b = (const float*)d_in[4];
  const float* V1_w = (const float*)d_in[5];
  const float* V1_b = (const float*)d_in[6];
  const float* V2_w = (const float*)d_in[7];
  const float* V2_b = (const float*)d_in[8];
  float* out = (float*)d_out;

  size_t off = 0;
  auto alloc = [&](size_t bytes) {
    void* p = (char*)d_ws + off;
    off += (bytes + 255) & ~(size_t)255;
    return p;
  };
  bf16_t* Wbf = (bf16_t*)alloc((size_t)Hn * Dn * 2);
  bf16_t* Uhi = (bf16_t*)alloc((size_t)Hn * Hn * 2);
  bf16_t* Ulo = (bf16_t*)alloc((size_t)Hn * Hn * 2);
  bf16_t* V1bf = (bf16_t*)alloc((size_t)Hn * Hn * 2);
  bf16_t* XW = (bf16_t*)alloc((size_t)Bn * Tn * Hn * 2);
  float* Z1 = (float*)alloc((size_t)Bn * Hn * 4);
  unsigned* slots = (unsigned*)alloc((size_t)NB * 32 * 4);  // 16 KB, 128B/slot

  // h chain: rotation if the workspace fits Tn+1 virgin slots, else ping-pong.
  const size_t slot_bytes = (size_t)Bn * Hn * 2;  // 256 KB
  const size_t rot_bytes = (size_t)(Tn + 1) * slot_bytes;
  const int rot = (ws_size - off) >= (rot_bytes + 256) ? 1 : 0;
  bf16_t* Hc = (bf16_t*)alloc(rot ? rot_bytes : 2 * slot_bytes);
  (void)ws_size;

  (void)hipFuncSetAttribute((const void*)scan_k,
                            hipFuncAttributeMaxDynamicSharedMemorySize, 133120);

  cvt_bf16_k<<<(Hn * Dn / 4 + 255) / 256, 256, 0, stream>>>(W_w, Wbf, Hn * Dn / 4);
  cvt_hilo_k<<<(Hn * Hn / 4 + 255) / 256, 256, 0, stream>>>(U_w, Uhi, Ulo, Hn * Hn / 4);
  cvt_bf16_k<<<(Hn * Hn / 4 + 255) / 256, 256, 0, stream>>>(V1_w, V1bf, Hn * Hn / 4);

  gemm_xw_k<<<dim3(Hn / 128, (Bn * Tn) / 128), 256, 0, stream>>>(inputs, Wbf, W_b, XW);

  (void)hipMemsetAsync(Hc, 0, slot_bytes, stream);  // slot 0 = h_0 = zeros
  (void)hipMemsetAsync(slots, 0, (size_t)NB * 32 * 4, stream);

  scan_k<<<NB, 256, 133120, stream>>>(Uhi, Ulo, U_b, XW, Hc, (long)Bn * Hn, rot,
                                      V1bf, V1_b, Z1, V2_w, V2_b, out, slots);
}

// Round 4
// 4122.802 us; speedup vs baseline: 1.9095x; 1.6492x over previous
//
#include <hip/hip_runtime.h>
#include <math.h>

typedef __bf16 bf16_t;
typedef __bf16 bf16x4 __attribute__((ext_vector_type(4)));
typedef __bf16 bf16x8 __attribute__((ext_vector_type(8)));
typedef float f32x4 __attribute__((ext_vector_type(4)));
typedef unsigned long long u64;

#define MFMA_16x16x32(A, B, C) __builtin_amdgcn_mfma_f32_16x16x32_bf16((A), (B), (C), 0, 0, 0)

static constexpr int Bn = 64;    // batch
static constexpr int Tn = 512;   // time
static constexpr int Dn = 1024;  // input dim
static constexpr int Hn = 2048;  // hidden
static constexpr int Cn = 5;     // classes
static constexpr int NGB = 128;  // blocks per batch-group
static constexpr int NGRP = 2;   // batch groups (32 rows each)
static constexpr int NBT = NGB * NGRP;  // 256 blocks = full GPU

// LDS swizzle for the xw GEMM tiles (32 bf16 = 64B rows)
#define SWZ64(row, kb)  ((((row) * 64) + (kb)) ^ (((row) & 3) << 4))

// ---------------- conversion kernels ----------------
__global__ __launch_bounds__(256) void cvt_bf16_k(const float* __restrict__ in,
                                                  bf16_t* __restrict__ out, int n4) {
  int i = blockIdx.x * 256 + threadIdx.x;
  if (i >= n4) return;
  float4 v = reinterpret_cast<const float4*>(in)[i];
  bf16x4 o;
  o[0] = (bf16_t)v.x; o[1] = (bf16_t)v.y; o[2] = (bf16_t)v.z; o[3] = (bf16_t)v.w;
  reinterpret_cast<bf16x4*>(out)[i] = o;
}

__global__ __launch_bounds__(256) void cvt_hilo_k(const float* __restrict__ in,
                                                  bf16_t* __restrict__ hi,
                                                  bf16_t* __restrict__ lo, int n4) {
  int i = blockIdx.x * 256 + threadIdx.x;
  if (i >= n4) return;
  float4 v = reinterpret_cast<const float4*>(in)[i];
  float f[4] = {v.x, v.y, v.z, v.w};
  bf16x4 h, l;
#pragma unroll
  for (int j = 0; j < 4; ++j) {
    bf16_t hb = (bf16_t)f[j];
    h[j] = hb;
    l[j] = (bf16_t)(f[j] - (float)hb);
  }
  reinterpret_cast<bf16x4*>(hi)[i] = h;
  reinterpret_cast<bf16x4*>(lo)[i] = l;
}

// ---------------- xw projection GEMM ----------------
__global__ __launch_bounds__(256) void gemm_xw_k(const float* __restrict__ A,
                                                 const bf16_t* __restrict__ Bw,
                                                 const float* __restrict__ bias,
                                                 bf16_t* __restrict__ C) {
  constexpr int K = Dn;
  constexpr int N = Hn;
  constexpr int NT = K / 32;
  __shared__ char As[2][128 * 64];
  __shared__ char Bs[2][128 * 64];

  const int tid = threadIdx.x;
  const int lane = tid & 63;
  const int wv = tid >> 6;
  const int wm = (wv >> 1) * 64;
  const int wn = (wv & 1) * 64;
  const int cl = lane & 15;
  const int kh = lane >> 4;
  const long m0 = (long)blockIdx.y * 128;
  const long n0 = (long)blockIdx.x * 128;

  const int srow = tid >> 1;
  const int scolb = (tid & 1) * 32;

  f32x4 acc[4][4] = {};
  float4 pa[4];
  uint4 pb[2];

  auto issue = [&](int kt) {
    const float* ap = A + (m0 + srow) * K + kt * 32 + (tid & 1) * 16;
#pragma unroll
    for (int i = 0; i < 4; ++i) pa[i] = reinterpret_cast<const float4*>(ap)[i];
    const bf16_t* bp = Bw + (n0 + srow) * K + kt * 32 + (tid & 1) * 16;
    pb[0] = reinterpret_cast<const uint4*>(bp)[0];
    pb[1] = reinterpret_cast<const uint4*>(bp)[1];
  };
  auto commit = [&](int buf) {
    bf16x8 a0, a1;
    a0[0] = (bf16_t)pa[0].x; a0[1] = (bf16_t)pa[0].y; a0[2] = (bf16_t)pa[0].z; a0[3] = (bf16_t)pa[0].w;
    a0[4] = (bf16_t)pa[1].x; a0[5] = (bf16_t)pa[1].y; a0[6] = (bf16_t)pa[1].z; a0[7] = (bf16_t)pa[1].w;
    a1[0] = (bf16_t)pa[2].x; a1[1] = (bf16_t)pa[2].y; a1[2] = (bf16_t)pa[2].z; a1[3] = (bf16_t)pa[2].w;
    a1[4] = (bf16_t)pa[3].x; a1[5] = (bf16_t)pa[3].y; a1[6] = (bf16_t)pa[3].z; a1[7] = (bf16_t)pa[3].w;
    *reinterpret_cast<bf16x8*>(&As[buf][SWZ64(srow, scolb)]) = a0;
    *reinterpret_cast<bf16x8*>(&As[buf][SWZ64(srow, scolb + 16)]) = a1;
    *reinterpret_cast<uint4*>(&Bs[buf][SWZ64(srow, scolb)]) = pb[0];
    *reinterpret_cast<uint4*>(&Bs[buf][SWZ64(srow, scolb + 16)]) = pb[1];
  };

  issue(0);
  commit(0);
  for (int kt = 0; kt < NT; ++kt) {
    const int buf = kt & 1;
    __syncthreads();
    if (kt + 1 < NT) issue(kt + 1);
    bf16x8 af[4], bfr[4];
#pragma unroll
    for (int i = 0; i < 4; ++i)
      af[i] = *reinterpret_cast<const bf16x8*>(&As[buf][SWZ64(wm + i * 16 + cl, kh * 16)]);
#pragma unroll
    for (int j = 0; j < 4; ++j)
      bfr[j] = *reinterpret_cast<const bf16x8*>(&Bs[buf][SWZ64(wn + j * 16 + cl, kh * 16)]);
#pragma unroll
    for (int i = 0; i < 4; ++i)
#pragma unroll
      for (int j = 0; j < 4; ++j)
        acc[i][j] = MFMA_16x16x32(af[i], bfr[j], acc[i][j]);
    if (kt + 1 < NT) commit((kt + 1) & 1);
  }

  const int rl4 = kh * 4;
#pragma unroll
  for (int j = 0; j < 4; ++j) {
    const long gcol = n0 + wn + j * 16 + cl;
    const float bv = bias[gcol];
#pragma unroll
    for (int i = 0; i < 4; ++i) {
      const long grow = m0 + wm + i * 16 + rl4;
#pragma unroll
      for (int q = 0; q < 4; ++q)
        C[(grow + q) * N + gcol] = (bf16_t)(acc[i][j][q] + bv);
    }
  }
}

// ---------------- persistent scan kernel ----------------
// Round-4 structure: BATCH-SPLIT GROUPS. 256 blocks = 2 groups x 128.
// Group g owns batch rows 32g..32g+31 and runs an independent 512-step scan
// with GROUP-LOCAL barriers (groups drift freely; they only meet at the
// final full-grid barrier before the head).
// Within a block: 16 output cols (n0), 4 waves = 2 row-tiles x 2 k-halves.
// Each wave reads 16 rows x 1024 k of h (32KB: HALF the old serial load
// stream) and does 64 MFMA; k-half partials reduce through 4KB LDS scratch.
// Coherence (round-3, kept): h stores sc0sc1 -> MALL, acked before flag;
// h loads plain cached on virgin rotated slots (no fence). Fallback rot=0:
// ping-pong + per-step acquire fence.
__global__ __launch_bounds__(256, 1) void scan_k(
    const bf16_t* __restrict__ Uhi, const bf16_t* __restrict__ Ulo,
    const float* __restrict__ Ub, const bf16_t* __restrict__ XW,
    bf16_t* __restrict__ Hc, long Hstep, int rot,
    const bf16_t* __restrict__ V1w, const float* __restrict__ V1b,
    float* __restrict__ Z1,
    const float* __restrict__ V2w, const float* __restrict__ V2b,
    float* __restrict__ out, unsigned* __restrict__ slots) {
  extern __shared__ char smem[];
  char* Uh_s = smem;                        // 64 KB
  char* Ul_s = smem + 65536;                // 64 KB
  float* red = (float*)(smem + 131072);     // 4 KB k-half partial scratch [4][16][16]

  const int tid = threadIdx.x;
  const int lane = tid & 63;
  const int wv = tid >> 6;
  const int cl = lane & 15;
  const int kh = lane >> 4;
  const int bid = blockIdx.x;
  const int g = bid >> 7;              // batch group (0/1)
  const int j = bid & (NGB - 1);       // group-local block id
  const int n0 = j * 16;               // owned columns
  const int r = wv >> 1;               // row-tile (0/1) within group slice
  const int kk = wv & 1;               // k-half (0/1)
  const int row0 = 32 * g + 16 * r;    // global batch row base for this wave
  unsigned* gslots = slots + (size_t)g * NGB * 32;

  // ---- stage U slice into LDS (once) ----
  {
    const int col = tid >> 4;
    const int seg = tid & 15;
    const char* srch = reinterpret_cast<const char*>(Uhi + (long)(n0 + col) * Hn);
    const char* srcl = reinterpret_cast<const char*>(Ulo + (long)(n0 + col) * Hn);
#pragma unroll
    for (int c = 0; c < 16; ++c) {
      const int byteoff = seg * 16 + c * 256;
      uint4 vh = *reinterpret_cast<const uint4*>(srch + byteoff);
      uint4 vl = *reinterpret_cast<const uint4*>(srcl + byteoff);
      const int sw = col * 4096 + (byteoff ^ ((col & 7) << 4));
      *reinterpret_cast<uint4*>(Uh_s + sw) = vh;
      *reinterpret_cast<uint4*>(Ul_s + sw) = vl;
    }
  }
  __syncthreads();

  const int lds_base = cl * 4096;
  const int lds_x = (cl & 7) << 4;
  const int kbase = kk * 2048;         // byte offset of this wave's k-half in LDS rows
  // store-side mapping (waves kk==0 only): one coalesced u64 per lane
  const int st_row = lane >> 2;        // 0..15
  const int st_cg = lane & 3;          // col group *4
  const bool storer = (kk == 0);

  float4 bv4 = {0.f, 0.f, 0.f, 0.f};
  if (storer) bv4 = *reinterpret_cast<const float4*>(Ub + n0 + st_cg * 4);
  const long xw_off = (long)(row0 + st_row) * (Tn * Hn) + n0 + st_cg * 4;

  // prefetch xw add-path for t=0 (storing lanes)
  bf16x4 ad = {};
  if (storer) ad = *reinterpret_cast<const bf16x4*>(XW + xw_off);

  // h slot pointers: t reads hin, writes hout.
  bf16_t* hin = Hc;            // slot 0 = zeros
  bf16_t* hout = Hc + Hstep;   // slot 1

  for (int t = 0; t < Tn; ++t) {
    const bf16_t* arow = hin + (long)(row0 + cl) * Hn + kk * 1024 + kh * 8;

    f32x4 ah0 = {}, ah1 = {}, al0 = {}, al1 = {};
#pragma unroll
    for (int it = 0; it < 16; ++it) {
      // plain cached 16-B loads: fresh by construction (virgin slot address)
      bf16x8 a0 = *reinterpret_cast<const bf16x8*>(arow + it * 64);
      bf16x8 a1 = *reinterpret_cast<const bf16x8*>(arow + it * 64 + 32);
      const int kb0 = kbase + it * 128 + kh * 16;
      const int kb1 = kb0 + 64;
      bf16x8 bh0 = *reinterpret_cast<const bf16x8*>(Uh_s + lds_base + (kb0 ^ lds_x));
      bf16x8 bl0 = *reinterpret_cast<const bf16x8*>(Ul_s + lds_base + (kb0 ^ lds_x));
      bf16x8 bh1 = *reinterpret_cast<const bf16x8*>(Uh_s + lds_base + (kb1 ^ lds_x));
      bf16x8 bl1 = *reinterpret_cast<const bf16x8*>(Ul_s + lds_base + (kb1 ^ lds_x));
      ah0 = MFMA_16x16x32(a0, bh0, ah0);
      al0 = MFMA_16x16x32(a0, bl0, al0);
      ah1 = MFMA_16x16x32(a1, bh1, ah1);
      al1 = MFMA_16x16x32(a1, bl1, al1);
    }

    // k-half partials -> LDS
#pragma unroll
    for (int q = 0; q < 4; ++q)
      red[wv * 256 + (kh * 4 + q) * 16 + cl] = ah0[q] + ah1[q] + al0[q] + al1[q];
    __syncthreads();

    // waves kk==0: combine k-halves, bias+xw+relu, one coalesced sc0sc1 store
    if (storer) {
      bf16x4 hv;
#pragma unroll
      for (int i = 0; i < 4; ++i) {
        const int ri = st_row * 16 + st_cg * 4 + i;
        float v = red[wv * 256 + ri] + red[(wv + 1) * 256 + ri] +
                  ((const float*)&bv4)[i] + (float)ad[i];
        hv[i] = (bf16_t)fmaxf(v, 0.f);
      }
      __hip_atomic_store(
          reinterpret_cast<u64*>(hout + (long)(row0 + st_row) * Hn + n0 + st_cg * 4),
          *reinterpret_cast<const u64*>(&hv), __ATOMIC_RELAXED,
          __HIP_MEMORY_SCOPE_AGENT);
    }

    // ---- group-local broadcast barrier ----
    const unsigned tgt = (unsigned)(t + 1);
    __syncthreads();  // drains vmcnt(0): all sc1 h-stores acked at coherence point
    asm volatile("" ::: "memory");
    if (tid == 0)
      __hip_atomic_store(gslots + (size_t)j * 32, tgt,
                         __ATOMIC_RELAXED, __HIP_MEMORY_SCOPE_AGENT);

    // prefetch XW for t+1 — hides under the poll
    bf16x4 adn = {};
    if (storer && (t + 1 < Tn))
      adn = *reinterpret_cast<const bf16x4*>(XW + xw_off + (long)(t + 1) * Hn);

    if (tid < 64) {  // wave 0 polls this group's 128 slots
      for (;;) {
        unsigned a = __hip_atomic_load(gslots + (size_t)tid * 32,
                                       __ATOMIC_RELAXED, __HIP_MEMORY_SCOPE_AGENT);
        unsigned b = __hip_atomic_load(gslots + (size_t)(tid + 64) * 32,
                                       __ATOMIC_RELAXED, __HIP_MEMORY_SCOPE_AGENT);
        if (__all((a >= tgt) && (b >= tgt))) break;
      }
      // rotation: no fence needed (virgin addresses can't be stale).
      if (!rot) __builtin_amdgcn_fence(__ATOMIC_ACQUIRE, "agent");
    }
    asm volatile("" ::: "memory");
    __syncthreads();

    ad = adn;

    // advance slots
    bf16_t* nn = hout;
    hout = rot ? (hout + Hstep) : hin;
    hin = nn;
  }

  // ---- V1 layer: z1 = relu(h_last @ V1^T + b1) for this group's 32 rows ----
  {
    const bf16_t* arow = hin + (long)(row0 + cl) * Hn + kk * 1024 + kh * 8;
    const bf16_t* vrow = V1w + (long)(n0 + cl) * Hn + kk * 1024 + kh * 8;
    f32x4 z0 = {}, z1a = {};
#pragma unroll
    for (int it = 0; it < 16; ++it) {
      bf16x8 a0 = *reinterpret_cast<const bf16x8*>(arow + it * 64);
      bf16x8 a1 = *reinterpret_cast<const bf16x8*>(arow + it * 64 + 32);
      bf16x8 b0 = *reinterpret_cast<const bf16x8*>(vrow + it * 64);
      bf16x8 b1 = *reinterpret_cast<const bf16x8*>(vrow + it * 64 + 32);
      z0 = MFMA_16x16x32(a0, b0, z0);
      z1a = MFMA_16x16x32(a1, b1, z1a);
    }
#pragma unroll
    for (int q = 0; q < 4; ++q)
      red[wv * 256 + (kh * 4 + q) * 16 + cl] = z0[q] + z1a[q];
    __syncthreads();
    if (storer) {
      float4 vb = *reinterpret_cast<const float4*>(V1b + n0 + st_cg * 4);
      float4 o;
#pragma unroll
      for (int i = 0; i < 4; ++i) {
        const int ri = st_row * 16 + st_cg * 4 + i;
        ((float*)&o)[i] = fmaxf(red[wv * 256 + ri] + red[(wv + 1) * 256 + ri] +
                                ((const float*)&vb)[i], 0.f);
      }
      *reinterpret_cast<float4*>(Z1 + (long)(row0 + st_row) * Hn + n0 + st_cg * 4) = o;
    }
  }

  // ---- FULL-grid barrier before head reads Z1 (release + acquire, once) ----
  {
    const unsigned tgt = (unsigned)(Tn + 1);
    __syncthreads();
    if (tid == 0)
      __hip_atomic_store(slots + (size_t)bid * 32, tgt,
                         __ATOMIC_RELEASE, __HIP_MEMORY_SCOPE_AGENT);
    if (tid < 64) {
      for (;;) {
        unsigned a = __hip_atomic_load(slots + (size_t)tid * 32,
                                       __ATOMIC_RELAXED, __HIP_MEMORY_SCOPE_AGENT);
        unsigned b = __hip_atomic_load(slots + (size_t)(tid + 64) * 32,
                                       __ATOMIC_RELAXED, __HIP_MEMORY_SCOPE_AGENT);
        unsigned c = __hip_atomic_load(slots + (size_t)(tid + 128) * 32,
                                       __ATOMIC_RELAXED, __HIP_MEMORY_SCOPE_AGENT);
        unsigned d = __hip_atomic_load(slots + (size_t)(tid + 192) * 32,
                                       __ATOMIC_RELAXED, __HIP_MEMORY_SCOPE_AGENT);
        if (__all((a >= tgt) && (b >= tgt) && (c >= tgt) && (d >= tgt))) break;
      }
      __builtin_amdgcn_fence(__ATOMIC_ACQUIRE, "agent");
    }
    __syncthreads();
  }

  // ---- head: z2 = relu(z1 @ V2^T + b2); out = log_softmax ----
  if (bid < Bn) {
    const int b = bid;
    float p[Cn] = {0.f, 0.f, 0.f, 0.f, 0.f};
    for (int jj = tid; jj < Hn; jj += 256) {
      const float x = Z1[(long)b * Hn + jj];
#pragma unroll
      for (int c = 0; c < Cn; ++c) p[c] += x * V2w[(long)c * Hn + jj];
    }
#pragma unroll
    for (int c = 0; c < Cn; ++c)
      for (int off = 32; off; off >>= 1) p[c] += __shfl_down(p[c], off, 64);

    float* redh = reinterpret_cast<float*>(smem);
    if (lane == 0) {
#pragma unroll
      for (int c = 0; c < Cn; ++c) redh[c * 4 + wv] = p[c];
    }
    __syncthreads();
    if (tid == 0) {
      float z[Cn];
      float mx = 0.f;
#pragma unroll
      for (int c = 0; c < Cn; ++c) {
        z[c] = redh[c * 4 + 0] + redh[c * 4 + 1] + redh[c * 4 + 2] + redh[c * 4 + 3] + V2b[c];
        z[c] = fmaxf(z[c], 0.f);
        mx = fmaxf(mx, z[c]);
      }
      float s = 0.f;
#pragma unroll
      for (int c = 0; c < Cn; ++c) s += expf(z[c] - mx);
      const float ls = logf(s);
#pragma unroll
      for (int c = 0; c < Cn; ++c) out[b * Cn + c] = z[c] - mx - ls;
    }
  }
}

// ---------------- host ----------------
extern "C" void kernel_launch(void* const* d_in, const int* in_sizes, int n_in,
                              void* d_out, int out_size, void* d_ws, size_t ws_size,
                              hipStream_t stream) {
  const float* inputs = (const float*)d_in[0];
  const float* W_w = (const float*)d_in[1];
  const float* W_b = (const float*)d_in[2];
  const float* U_w = (const float*)d_in[3];
  const float* U_b = (const float*)d_in[4];
  const float* V1_w = (const float*)d_in[5];
  const float* V1_b = (const float*)d_in[6];
  const float* V2_w = (const float*)d_in[7];
  const float* V2_b = (const float*)d_in[8];
  float* out = (float*)d_out;

  size_t off = 0;
  auto alloc = [&](size_t bytes) {
    void* p = (char*)d_ws + off;
    off += (bytes + 255) & ~(size_t)255;
    return p;
  };
  bf16_t* Wbf = (bf16_t*)alloc((size_t)Hn * Dn * 2);
  bf16_t* Uhi = (bf16_t*)alloc((size_t)Hn * Hn * 2);
  bf16_t* Ulo = (bf16_t*)alloc((size_t)Hn * Hn * 2);
  bf16_t* V1bf = (bf16_t*)alloc((size_t)Hn * Hn * 2);
  bf16_t* XW = (bf16_t*)alloc((size_t)Bn * Tn * Hn * 2);
  float* Z1 = (float*)alloc((size_t)Bn * Hn * 4);
  unsigned* slots = (unsigned*)alloc((size_t)NBT * 32 * 4);  // 32 KB, 128B/slot

  // h chain: rotation if the workspace fits Tn+1 virgin slots, else ping-pong.
  const size_t slot_bytes = (size_t)Bn * Hn * 2;  // 256 KB
  const size_t rot_bytes = (size_t)(Tn + 1) * slot_bytes;
  const int rot = (ws_size - off) >= (rot_bytes + 256) ? 1 : 0;
  bf16_t* Hc = (bf16_t*)alloc(rot ? rot_bytes : 2 * slot_bytes);
  (void)ws_size;

  (void)hipFuncSetAttribute((const void*)scan_k,
                            hipFuncAttributeMaxDynamicSharedMemorySize, 135168);

  cvt_bf16_k<<<(Hn * Dn / 4 + 255) / 256, 256, 0, stream>>>(W_w, Wbf, Hn * Dn / 4);
  cvt_hilo_k<<<(Hn * Hn / 4 + 255) / 256, 256, 0, stream>>>(U_w, Uhi, Ulo, Hn * Hn / 4);
  cvt_bf16_k<<<(Hn * Hn / 4 + 255) / 256, 256, 0, stream>>>(V1_w, V1bf, Hn * Hn / 4);

  gemm_xw_k<<<dim3(Hn / 128, (Bn * Tn) / 128), 256, 0, stream>>>(inputs, Wbf, W_b, XW);

  (void)hipMemsetAsync(Hc, 0, slot_bytes, stream);  // slot 0 = h_0 = zeros
  (void)hipMemsetAsync(slots, 0, (size_t)NBT * 32 * 4, stream);

  scan_k<<<NBT, 256, 135168, stream>>>(Uhi, Ulo, U_b, XW, Hc, (long)Bn * Hn, rot,
                                       V1bf, V1_b, Z1, V2_w, V2_b, out, slots);
}

// Round 5
// 3305.284 us; speedup vs baseline: 2.3818x; 1.2473x over previous
//
#include <hip/hip_runtime.h>
#include <math.h>

typedef __bf16 bf16_t;
typedef __bf16 bf16x4 __attribute__((ext_vector_type(4)));
typedef __bf16 bf16x8 __attribute__((ext_vector_type(8)));
typedef float f32x4 __attribute__((ext_vector_type(4)));
typedef unsigned long long u64;

#define MFMA_16x16x32(A, B, C) __builtin_amdgcn_mfma_f32_16x16x32_bf16((A), (B), (C), 0, 0, 0)

static constexpr int Bn = 64;    // batch
static constexpr int Tn = 512;   // time
static constexpr int Dn = 1024;  // input dim
static constexpr int Hn = 2048;  // hidden
static constexpr int Cn = 5;     // classes
static constexpr int NGB = 128;  // blocks per batch-group
static constexpr int NGRP = 2;   // batch groups (32 rows each)
static constexpr int NBT = NGB * NGRP;  // 256 blocks = full GPU

// LDS swizzle for the xw GEMM tiles (32 bf16 = 64B rows)
#define SWZ64(row, kb)  ((((row) * 64) + (kb)) ^ (((row) & 3) << 4))

// ---------------- conversion kernels ----------------
__global__ __launch_bounds__(256) void cvt_bf16_k(const float* __restrict__ in,
                                                  bf16_t* __restrict__ out, int n4) {
  int i = blockIdx.x * 256 + threadIdx.x;
  if (i >= n4) return;
  float4 v = reinterpret_cast<const float4*>(in)[i];
  bf16x4 o;
  o[0] = (bf16_t)v.x; o[1] = (bf16_t)v.y; o[2] = (bf16_t)v.z; o[3] = (bf16_t)v.w;
  reinterpret_cast<bf16x4*>(out)[i] = o;
}

__global__ __launch_bounds__(256) void cvt_hilo_k(const float* __restrict__ in,
                                                  bf16_t* __restrict__ hi,
                                                  bf16_t* __restrict__ lo, int n4) {
  int i = blockIdx.x * 256 + threadIdx.x;
  if (i >= n4) return;
  float4 v = reinterpret_cast<const float4*>(in)[i];
  float f[4] = {v.x, v.y, v.z, v.w};
  bf16x4 h, l;
#pragma unroll
  for (int j = 0; j < 4; ++j) {
    bf16_t hb = (bf16_t)f[j];
    h[j] = hb;
    l[j] = (bf16_t)(f[j] - (float)hb);
  }
  reinterpret_cast<bf16x4*>(hi)[i] = h;
  reinterpret_cast<bf16x4*>(lo)[i] = l;
}

// ---------------- xw projection GEMM ----------------
__global__ __launch_bounds__(256) void gemm_xw_k(const float* __restrict__ A,
                                                 const bf16_t* __restrict__ Bw,
                                                 const float* __restrict__ bias,
                                                 bf16_t* __restrict__ C) {
  constexpr int K = Dn;
  constexpr int N = Hn;
  constexpr int NT = K / 32;
  __shared__ char As[2][128 * 64];
  __shared__ char Bs[2][128 * 64];

  const int tid = threadIdx.x;
  const int lane = tid & 63;
  const int wv = tid >> 6;
  const int wm = (wv >> 1) * 64;
  const int wn = (wv & 1) * 64;
  const int cl = lane & 15;
  const int kh = lane >> 4;
  const long m0 = (long)blockIdx.y * 128;
  const long n0 = (long)blockIdx.x * 128;

  const int srow = tid >> 1;
  const int scolb = (tid & 1) * 32;

  f32x4 acc[4][4] = {};
  float4 pa[4];
  uint4 pb[2];

  auto issue = [&](int kt) {
    const float* ap = A + (m0 + srow) * K + kt * 32 + (tid & 1) * 16;
#pragma unroll
    for (int i = 0; i < 4; ++i) pa[i] = reinterpret_cast<const float4*>(ap)[i];
    const bf16_t* bp = Bw + (n0 + srow) * K + kt * 32 + (tid & 1) * 16;
    pb[0] = reinterpret_cast<const uint4*>(bp)[0];
    pb[1] = reinterpret_cast<const uint4*>(bp)[1];
  };
  auto commit = [&](int buf) {
    bf16x8 a0, a1;
    a0[0] = (bf16_t)pa[0].x; a0[1] = (bf16_t)pa[0].y; a0[2] = (bf16_t)pa[0].z; a0[3] = (bf16_t)pa[0].w;
    a0[4] = (bf16_t)pa[1].x; a0[5] = (bf16_t)pa[1].y; a0[6] = (bf16_t)pa[1].z; a0[7] = (bf16_t)pa[1].w;
    a1[0] = (bf16_t)pa[2].x; a1[1] = (bf16_t)pa[2].y; a1[2] = (bf16_t)pa[2].z; a1[3] = (bf16_t)pa[2].w;
    a1[4] = (bf16_t)pa[3].x; a1[5] = (bf16_t)pa[3].y; a1[6] = (bf16_t)pa[3].z; a1[7] = (bf16_t)pa[3].w;
    *reinterpret_cast<bf16x8*>(&As[buf][SWZ64(srow, scolb)]) = a0;
    *reinterpret_cast<bf16x8*>(&As[buf][SWZ64(srow, scolb + 16)]) = a1;
    *reinterpret_cast<uint4*>(&Bs[buf][SWZ64(srow, scolb)]) = pb[0];
    *reinterpret_cast<uint4*>(&Bs[buf][SWZ64(srow, scolb + 16)]) = pb[1];
  };

  issue(0);
  commit(0);
  for (int kt = 0; kt < NT; ++kt) {
    const int buf = kt & 1;
    __syncthreads();
    if (kt + 1 < NT) issue(kt + 1);
    bf16x8 af[4], bfr[4];
#pragma unroll
    for (int i = 0; i < 4; ++i)
      af[i] = *reinterpret_cast<const bf16x8*>(&As[buf][SWZ64(wm + i * 16 + cl, kh * 16)]);
#pragma unroll
    for (int j = 0; j < 4; ++j)
      bfr[j] = *reinterpret_cast<const bf16x8*>(&Bs[buf][SWZ64(wn + j * 16 + cl, kh * 16)]);
#pragma unroll
    for (int i = 0; i < 4; ++i)
#pragma unroll
      for (int j = 0; j < 4; ++j)
        acc[i][j] = MFMA_16x16x32(af[i], bfr[j], acc[i][j]);
    if (kt + 1 < NT) commit((kt + 1) & 1);
  }

  const int rl4 = kh * 4;
#pragma unroll
  for (int j = 0; j < 4; ++j) {
    const long gcol = n0 + wn + j * 16 + cl;
    const float bv = bias[gcol];
#pragma unroll
    for (int i = 0; i < 4; ++i) {
      const long grow = m0 + wm + i * 16 + rl4;
#pragma unroll
      for (int q = 0; q < 4; ++q)
        C[(grow + q) * N + gcol] = (bf16_t)(acc[i][j][q] + bv);
    }
  }
}

// ---------------- persistent scan kernel ----------------
// Round-5 structure: 256 blocks x 512 THREADS (8 waves), 1 block/CU,
// 2 waves/SIMD. 2 batch-groups x 128 blocks, group-local barriers (r4).
// Within a block: 16 output cols, 8 waves = 2 row-tiles x 4 k-quarters.
// Each wave reads 16 rows x 512 k of h (16KB serial stream: HALF of r4),
// all 16 loads preloaded into VGPRs before the MFMA loop (max MLP);
// 4 k-quarter partials reduce through 8KB LDS scratch.
// Coherence (r3, kept): h stores sc0sc1 -> MALL, acked before flag;
// h loads plain cached on virgin rotated slots (no fence). Fallback rot=0:
// ping-pong + per-step acquire fence.
__global__ __launch_bounds__(512, 1) void scan_k(
    const bf16_t* __restrict__ Uhi, const bf16_t* __restrict__ Ulo,
    const float* __restrict__ Ub, const bf16_t* __restrict__ XW,
    bf16_t* __restrict__ Hc, long Hstep, int rot,
    const bf16_t* __restrict__ V1w, const float* __restrict__ V1b,
    float* __restrict__ Z1,
    const float* __restrict__ V2w, const float* __restrict__ V2b,
    float* __restrict__ out, unsigned* __restrict__ slots) {
  extern __shared__ char smem[];
  char* Uh_s = smem;                        // 64 KB
  char* Ul_s = smem + 65536;                // 64 KB
  float* red = (float*)(smem + 131072);     // 8 KB k-quarter partial scratch [8][256]

  const int tid = threadIdx.x;
  const int lane = tid & 63;
  const int wv = tid >> 6;             // 0..7
  const int cl = lane & 15;
  const int kh = lane >> 4;
  const int bid = blockIdx.x;
  const int g = bid >> 7;              // batch group (0/1)
  const int j = bid & (NGB - 1);       // group-local block id
  const int n0 = j * 16;               // owned columns
  const int r = wv >> 2;               // row-tile (0/1) within group slice
  const int kq = wv & 3;               // k-quarter (0..3)
  const int row0 = 32 * g + 16 * r;    // global batch row base for this wave
  unsigned* gslots = slots + (size_t)g * NGB * 32;

  // ---- stage U slice into LDS (once; 512 threads: 32 segs x 16 cols) ----
  {
    const int col = tid >> 5;          // 0..15
    const int seg = tid & 31;          // 0..31
    const char* srch = reinterpret_cast<const char*>(Uhi + (long)(n0 + col) * Hn);
    const char* srcl = reinterpret_cast<const char*>(Ulo + (long)(n0 + col) * Hn);
#pragma unroll
    for (int c = 0; c < 8; ++c) {
      const int byteoff = seg * 16 + c * 512;
      uint4 vh = *reinterpret_cast<const uint4*>(srch + byteoff);
      uint4 vl = *reinterpret_cast<const uint4*>(srcl + byteoff);
      const int sw = col * 4096 + (byteoff ^ ((col & 7) << 4));
      *reinterpret_cast<uint4*>(Uh_s + sw) = vh;
      *reinterpret_cast<uint4*>(Ul_s + sw) = vl;
    }
  }
  __syncthreads();

  const int lds_base = cl * 4096;
  const int lds_x = (cl & 7) << 4;
  const int kbase = kq * 1024;         // byte offset of this wave's k-quarter
  // store-side mapping (waves kq==0 only): one coalesced u64 per lane
  const int st_row = lane >> 2;        // 0..15
  const int st_cg = lane & 3;          // col group *4
  const bool storer = (kq == 0);

  float4 bv4 = {0.f, 0.f, 0.f, 0.f};
  if (storer) bv4 = *reinterpret_cast<const float4*>(Ub + n0 + st_cg * 4);
  const long xw_off = (long)(row0 + st_row) * (Tn * Hn) + n0 + st_cg * 4;

  // prefetch xw add-path for t=0 (storing lanes)
  bf16x4 ad = {};
  if (storer) ad = *reinterpret_cast<const bf16x4*>(XW + xw_off);

  // h slot pointers: t reads hin, writes hout.
  bf16_t* hin = Hc;            // slot 0 = zeros
  bf16_t* hout = Hc + Hstep;   // slot 1

  for (int t = 0; t < Tn; ++t) {
    const bf16_t* arow = hin + (long)(row0 + cl) * Hn + kq * 512 + kh * 8;

    // preload ALL h fragments for this wave's k-quarter (16 outstanding loads)
    bf16x8 av0[8], av1[8];
#pragma unroll
    for (int it = 0; it < 8; ++it) {
      av0[it] = *reinterpret_cast<const bf16x8*>(arow + it * 64);
      av1[it] = *reinterpret_cast<const bf16x8*>(arow + it * 64 + 32);
    }

    f32x4 ah0 = {}, ah1 = {}, al0 = {}, al1 = {};
#pragma unroll
    for (int it = 0; it < 8; ++it) {
      const int kb0 = kbase + it * 128 + kh * 16;
      const int kb1 = kb0 + 64;
      bf16x8 bh0 = *reinterpret_cast<const bf16x8*>(Uh_s + lds_base + (kb0 ^ lds_x));
      bf16x8 bl0 = *reinterpret_cast<const bf16x8*>(Ul_s + lds_base + (kb0 ^ lds_x));
      bf16x8 bh1 = *reinterpret_cast<const bf16x8*>(Uh_s + lds_base + (kb1 ^ lds_x));
      bf16x8 bl1 = *reinterpret_cast<const bf16x8*>(Ul_s + lds_base + (kb1 ^ lds_x));
      ah0 = MFMA_16x16x32(av0[it], bh0, ah0);
      al0 = MFMA_16x16x32(av0[it], bl0, al0);
      ah1 = MFMA_16x16x32(av1[it], bh1, ah1);
      al1 = MFMA_16x16x32(av1[it], bl1, al1);
    }

    // k-quarter partials -> LDS
#pragma unroll
    for (int q = 0; q < 4; ++q)
      red[wv * 256 + (kh * 4 + q) * 16 + cl] = ah0[q] + ah1[q] + al0[q] + al1[q];
    __syncthreads();

    // waves kq==0: combine 4 k-quarters, bias+xw+relu, one coalesced store
    if (storer) {
      bf16x4 hv;
#pragma unroll
      for (int i = 0; i < 4; ++i) {
        const int ri = st_row * 16 + st_cg * 4 + i;
        float v = red[wv * 256 + ri] + red[(wv + 1) * 256 + ri] +
                  red[(wv + 2) * 256 + ri] + red[(wv + 3) * 256 + ri] +
                  ((const float*)&bv4)[i] + (float)ad[i];
        hv[i] = (bf16_t)fmaxf(v, 0.f);
      }
      __hip_atomic_store(
          reinterpret_cast<u64*>(hout + (long)(row0 + st_row) * Hn + n0 + st_cg * 4),
          *reinterpret_cast<const u64*>(&hv), __ATOMIC_RELAXED,
          __HIP_MEMORY_SCOPE_AGENT);
    }

    // ---- group-local broadcast barrier ----
    const unsigned tgt = (unsigned)(t + 1);
    __syncthreads();  // drains vmcnt(0): all sc1 h-stores acked at coherence point
    asm volatile("" ::: "memory");
    if (tid == 0)
      __hip_atomic_store(gslots + (size_t)j * 32, tgt,
                         __ATOMIC_RELAXED, __HIP_MEMORY_SCOPE_AGENT);

    // prefetch XW for t+1 — hides under the poll
    bf16x4 adn = {};
    if (storer && (t + 1 < Tn))
      adn = *reinterpret_cast<const bf16x4*>(XW + xw_off + (long)(t + 1) * Hn);

    if (tid < 64) {  // wave 0 polls this group's 128 slots
      for (;;) {
        unsigned a = __hip_atomic_load(gslots + (size_t)tid * 32,
                                       __ATOMIC_RELAXED, __HIP_MEMORY_SCOPE_AGENT);
        unsigned b = __hip_atomic_load(gslots + (size_t)(tid + 64) * 32,
                                       __ATOMIC_RELAXED, __HIP_MEMORY_SCOPE_AGENT);
        if (__all((a >= tgt) && (b >= tgt))) break;
      }
      // rotation: no fence needed (virgin addresses can't be stale).
      if (!rot) __builtin_amdgcn_fence(__ATOMIC_ACQUIRE, "agent");
    }
    asm volatile("" ::: "memory");
    __syncthreads();

    ad = adn;

    // advance slots
    bf16_t* nn = hout;
    hout = rot ? (hout + Hstep) : hin;
    hin = nn;
  }

  // ---- V1 layer: z1 = relu(h_last @ V1^T + b1) for this group's 32 rows ----
  {
    const bf16_t* arow = hin + (long)(row0 + cl) * Hn + kq * 512 + kh * 8;
    const bf16_t* vrow = V1w + (long)(n0 + cl) * Hn + kq * 512 + kh * 8;
    f32x4 z0 = {}, z1a = {};
#pragma unroll
    for (int it = 0; it < 8; ++it) {
      bf16x8 a0 = *reinterpret_cast<const bf16x8*>(arow + it * 64);
      bf16x8 a1 = *reinterpret_cast<const bf16x8*>(arow + it * 64 + 32);
      bf16x8 b0 = *reinterpret_cast<const bf16x8*>(vrow + it * 64);
      bf16x8 b1 = *reinterpret_cast<const bf16x8*>(vrow + it * 64 + 32);
      z0 = MFMA_16x16x32(a0, b0, z0);
      z1a = MFMA_16x16x32(a1, b1, z1a);
    }
#pragma unroll
    for (int q = 0; q < 4; ++q)
      red[wv * 256 + (kh * 4 + q) * 16 + cl] = z0[q] + z1a[q];
    __syncthreads();
    if (storer) {
      float4 vb = *reinterpret_cast<const float4*>(V1b + n0 + st_cg * 4);
      float4 o;
#pragma unroll
      for (int i = 0; i < 4; ++i) {
        const int ri = st_row * 16 + st_cg * 4 + i;
        ((float*)&o)[i] = fmaxf(red[wv * 256 + ri] + red[(wv + 1) * 256 + ri] +
                                red[(wv + 2) * 256 + ri] + red[(wv + 3) * 256 + ri] +
                                ((const float*)&vb)[i], 0.f);
      }
      *reinterpret_cast<float4*>(Z1 + (long)(row0 + st_row) * Hn + n0 + st_cg * 4) = o;
    }
  }

  // ---- FULL-grid barrier before head reads Z1 (release + acquire, once) ----
  {
    const unsigned tgt = (unsigned)(Tn + 1);
    __syncthreads();
    if (tid == 0)
      __hip_atomic_store(slots + (size_t)bid * 32, tgt,
                         __ATOMIC_RELEASE, __HIP_MEMORY_SCOPE_AGENT);
    if (tid < 64) {
      for (;;) {
        unsigned a = __hip_atomic_load(slots + (size_t)tid * 32,
                                       __ATOMIC_RELAXED, __HIP_MEMORY_SCOPE_AGENT);
        unsigned b = __hip_atomic_load(slots + (size_t)(tid + 64) * 32,
                                       __ATOMIC_RELAXED, __HIP_MEMORY_SCOPE_AGENT);
        unsigned c = __hip_atomic_load(slots + (size_t)(tid + 128) * 32,
                                       __ATOMIC_RELAXED, __HIP_MEMORY_SCOPE_AGENT);
        unsigned d = __hip_atomic_load(slots + (size_t)(tid + 192) * 32,
                                       __ATOMIC_RELAXED, __HIP_MEMORY_SCOPE_AGENT);
        if (__all((a >= tgt) && (b >= tgt) && (c >= tgt) && (d >= tgt))) break;
      }
      __builtin_amdgcn_fence(__ATOMIC_ACQUIRE, "agent");
    }
    __syncthreads();
  }

  // ---- head: z2 = relu(z1 @ V2^T + b2); out = log_softmax ----
  if (bid < Bn) {
    const int b = bid;
    float p[Cn] = {0.f, 0.f, 0.f, 0.f, 0.f};
    for (int jj = tid; jj < Hn; jj += 512) {
      const float x = Z1[(long)b * Hn + jj];
#pragma unroll
      for (int c = 0; c < Cn; ++c) p[c] += x * V2w[(long)c * Hn + jj];
    }
#pragma unroll
    for (int c = 0; c < Cn; ++c)
      for (int off = 32; off; off >>= 1) p[c] += __shfl_down(p[c], off, 64);

    float* redh = reinterpret_cast<float*>(smem);
    if (lane == 0) {
#pragma unroll
      for (int c = 0; c < Cn; ++c) redh[c * 8 + wv] = p[c];
    }
    __syncthreads();
    if (tid == 0) {
      float z[Cn];
      float mx = 0.f;
#pragma unroll
      for (int c = 0; c < Cn; ++c) {
        float s8 = 0.f;
#pragma unroll
        for (int w = 0; w < 8; ++w) s8 += redh[c * 8 + w];
        z[c] = fmaxf(s8 + V2b[c], 0.f);
        mx = fmaxf(mx, z[c]);
      }
      float s = 0.f;
#pragma unroll
      for (int c = 0; c < Cn; ++c) s += expf(z[c] - mx);
      const float ls = logf(s);
#pragma unroll
      for (int c = 0; c < Cn; ++c) out[b * Cn + c] = z[c] - mx - ls;
    }
  }
}

// ---------------- host ----------------
extern "C" void kernel_launch(void* const* d_in, const int* in_sizes, int n_in,
                              void* d_out, int out_size, void* d_ws, size_t ws_size,
                              hipStream_t stream) {
  const float* inputs = (const float*)d_in[0];
  const float* W_w = (const float*)d_in[1];
  const float* W_b = (const float*)d_in[2];
  const float* U_w = (const float*)d_in[3];
  const float* U_b = (const float*)d_in[4];
  const float* V1_w = (const float*)d_in[5];
  const float* V1_b = (const float*)d_in[6];
  const float* V2_w = (const float*)d_in[7];
  const float* V2_b = (const float*)d_in[8];
  float* out = (float*)d_out;

  size_t off = 0;
  auto alloc = [&](size_t bytes) {
    void* p = (char*)d_ws + off;
    off += (bytes + 255) & ~(size_t)255;
    return p;
  };
  bf16_t* Wbf = (bf16_t*)alloc((size_t)Hn * Dn * 2);
  bf16_t* Uhi = (bf16_t*)alloc((size_t)Hn * Hn * 2);
  bf16_t* Ulo = (bf16_t*)alloc((size_t)Hn * Hn * 2);
  bf16_t* V1bf = (bf16_t*)alloc((size_t)Hn * Hn * 2);
  bf16_t* XW = (bf16_t*)alloc((size_t)Bn * Tn * Hn * 2);
  float* Z1 = (float*)alloc((size_t)Bn * Hn * 4);
  unsigned* slots = (unsigned*)alloc((size_t)NBT * 32 * 4);  // 32 KB, 128B/slot

  // h chain: rotation if the workspace fits Tn+1 virgin slots, else ping-pong.
  const size_t slot_bytes = (size_t)Bn * Hn * 2;  // 256 KB
  const size_t rot_bytes = (size_t)(Tn + 1) * slot_bytes;
  const int rot = (ws_size - off) >= (rot_bytes + 256) ? 1 : 0;
  bf16_t* Hc = (bf16_t*)alloc(rot ? rot_bytes : 2 * slot_bytes);
  (void)ws_size;

  (void)hipFuncSetAttribute((const void*)scan_k,
                            hipFuncAttributeMaxDynamicSharedMemorySize, 139264);

  cvt_bf16_k<<<(Hn * Dn / 4 + 255) / 256, 256, 0, stream>>>(W_w, Wbf, Hn * Dn / 4);
  cvt_hilo_k<<<(Hn * Hn / 4 + 255) / 256, 256, 0, stream>>>(U_w, Uhi, Ulo, Hn * Hn / 4);
  cvt_bf16_k<<<(Hn * Hn / 4 + 255) / 256, 256, 0, stream>>>(V1_w, V1bf, Hn * Hn / 4);

  gemm_xw_k<<<dim3(Hn / 128, (Bn * Tn) / 128), 256, 0, stream>>>(inputs, Wbf, W_b, XW);

  (void)hipMemsetAsync(Hc, 0, slot_bytes, stream);  // slot 0 = h_0 = zeros
  (void)hipMemsetAsync(slots, 0, (size_t)NBT * 32 * 4, stream);

  scan_k<<<NBT, 512, 139264, stream>>>(Uhi, Ulo, U_b, XW, Hc, (long)Bn * Hn, rot,
                                       V1bf, V1_b, Z1, V2_w, V2_b, out, slots);
}